// Round 3
// baseline (356.575 us; speedup 1.0000x reference)
//
#include <hip/hip_runtime.h>

#define N_NODES 50000
#define N_EDGES 800000
#define D 64
#define BUCKET_NODES 64
#define BUCKET_SHIFT 6
#define N_BUCKETS ((N_NODES + BUCKET_NODES - 1) / BUCKET_NODES)  // 782
#define CAP 1536          // slots per bucket; mean load 1024, sigma 32 -> +16 sigma
#define RPT (CAP / 256)   // records per thread per chunk = 6

// ---------------------------------------------------------------------------
// One fused edge sweep: per-node degree histogram + coarse binning.
// Record = (dst << 16) | src  (both < 65536). Appends to 782 fixed regions:
// active write-lines ~50KB -> write-combines in L2 (no 64B-line amplification).
// ---------------------------------------------------------------------------
__global__ void bin_hist(const int* __restrict__ src, const int* __restrict__ dst,
                         int* __restrict__ counts, int* __restrict__ cursor,
                         unsigned int* __restrict__ binned) {
    int e = blockIdx.x * 256 + threadIdx.x;
    if (e < N_EDGES) {
        int s = src[e];
        int t = dst[e];
        atomicAdd(&counts[t], 1);
        int bu  = t >> BUCKET_SHIFT;
        int pos = atomicAdd(&cursor[bu], 1);
        if (pos < CAP) binned[bu * CAP + pos] = ((unsigned)t << 16) | (unsigned)s;
    }
}

// ---------------------------------------------------------------------------
// xws = rsqrt(deg+1) * (x @ W); also stores dis[row].
// ---------------------------------------------------------------------------
__global__ void xws_kernel(const float* __restrict__ x, const float* __restrict__ W,
                           const int* __restrict__ counts,
                           float* __restrict__ xws, float* __restrict__ dis) {
    __shared__ float Ws[D * D];
    __shared__ float xs[4][D];
    int tid = threadIdx.x;
    for (int i = tid; i < D * D; i += 256) Ws[i] = W[i];
    __syncthreads();

    int col = tid & 63;
    int r   = tid >> 6;
    int rowBase = blockIdx.x * 16;

    for (int g = 0; g < 4; ++g) {
        int row = rowBase + g * 4 + r;
        __syncthreads();
        if (row < N_NODES) xs[r][col] = x[row * D + col];
        __syncthreads();
        if (row < N_NODES) {
            float sum = 0.f;
            #pragma unroll
            for (int k = 0; k < D; ++k)
                sum = fmaf(xs[r][k], Ws[k * D + col], sum);
            float di = rsqrtf((float)counts[row] + 1.0f);
            xws[row * D + col] = di * sum;
            if (col == 0) dis[row] = di;
        }
    }
}

// ---------------------------------------------------------------------------
// Gather: one block per 64-node bucket. LDS counting-sort of the bucket's
// packed records, then wave-per-node segment consumption. lane = feature.
// out[i] = relu(b + dis_i * (xws_i + sum_{j->i} xws_j))
// ---------------------------------------------------------------------------
__global__ __launch_bounds__(256) void
gather_out(const unsigned int* __restrict__ binned, const int* __restrict__ cursor,
           const float* __restrict__ dis, const float* __restrict__ xws,
           const float* __restrict__ b, float* __restrict__ out) {
    __shared__ unsigned int sorted[CAP];
    __shared__ int hist_l[BUCKET_NODES];
    __shared__ int segoff_l[BUCKET_NODES];
    __shared__ int scnt_l[BUCKET_NODES];

    int bu   = blockIdx.x;
    int nb   = bu * BUCKET_NODES;
    int tid  = threadIdx.x;
    int wave = tid >> 6;
    int lane = tid & 63;

    int total = cursor[bu];
    if (total > CAP) total = CAP;
    const unsigned int* brec = binned + (size_t)bu * CAP;

    // accumulators: wave w owns local nodes w*16 .. w*16+15; init = self term
    float acc[16];
    #pragma unroll
    for (int i = 0; i < 16; ++i) {
        int n = nb + wave * 16 + i;
        acc[i] = (n < N_NODES) ? xws[n * D + lane] : 0.0f;
    }
    float bl = b[lane];

    // ---- load records into registers + LDS histogram ----
    if (tid < BUCKET_NODES) hist_l[tid] = 0;
    __syncthreads();

    unsigned int rec[RPT];
    #pragma unroll
    for (int u = 0; u < RPT; ++u) {
        int j = u * 256 + tid;
        if (j < total) {
            unsigned int v = brec[j];
            rec[u] = v;
            atomicAdd(&hist_l[(v >> 16) & (BUCKET_NODES - 1)], 1);
        } else {
            rec[u] = 0xFFFFFFFFu;
        }
    }
    __syncthreads();

    // ---- exclusive scan of 64 counters (wave 0, shfl-based) ----
    if (tid < 64) {
        int v = hist_l[tid];
        int s = v;
        #pragma unroll
        for (int off = 1; off < 64; off <<= 1) {
            int t = __shfl_up(s, off);
            if (tid >= off) s += t;
        }
        segoff_l[tid] = s - v;
        scnt_l[tid]   = s - v;
    }
    __syncthreads();

    // ---- scatter into sorted order (LDS atomics on 64 cursors) ----
    #pragma unroll
    for (int u = 0; u < RPT; ++u) {
        unsigned int v = rec[u];
        if (v != 0xFFFFFFFFu) {
            int pos = atomicAdd(&scnt_l[(v >> 16) & (BUCKET_NODES - 1)], 1);
            sorted[pos] = v;
        }
    }
    __syncthreads();

    // ---- consume: wave-per-node, coalesced 256B row gathers ----
    for (int i = 0; i < 16; ++i) {
        int nl  = wave * 16 + i;
        int off = segoff_l[nl];
        int cnt = hist_l[nl];
        int k = 0;
        for (; k + 1 < cnt; k += 2) {              // 2-way MLP
            int s0 = sorted[off + k] & 0xFFFF;
            int s1 = sorted[off + k + 1] & 0xFFFF;
            float v0 = xws[s0 * D + lane];
            float v1 = xws[s1 * D + lane];
            acc[i] += v0 + v1;
        }
        if (k < cnt) acc[i] += xws[(sorted[off + k] & 0xFFFF) * D + lane];
    }

    // ---- epilogue: bias + dis scale + relu ----
    #pragma unroll
    for (int i = 0; i < 16; ++i) {
        int n = nb + wave * 16 + i;
        if (n < N_NODES)
            out[n * D + lane] = fmaxf(bl + dis[n] * acc[i], 0.0f);
    }
}

// ---------------------------------------------------------------------------
extern "C" void kernel_launch(void* const* d_in, const int* in_sizes, int n_in,
                              void* d_out, int out_size, void* d_ws, size_t ws_size,
                              hipStream_t stream) {
    const float* x  = (const float*)d_in[0];
    const int*   ei = (const int*)d_in[1];   // [2, E] flat: src then dst
    const float* W  = (const float*)d_in[2];
    const float* b  = (const float*)d_in[3];

    const int* src = ei;
    const int* dst = ei + N_EDGES;
    float* out = (float*)d_out;

    // workspace layout (total ~18.0 MB)
    float*        xws    = (float*)d_ws;                      // 3.2e6 floats
    float*        dis    = xws + (size_t)N_NODES * D;         // 50000 floats
    int*          counts = (int*)(dis + N_NODES);             // 50000 ints
    int*          cursor = counts + N_NODES;                  // 784 ints (pad)
    unsigned int* binned = (unsigned int*)(cursor + 784);     // 782*1536 uints

    // zero counts + cursors (contiguous)
    hipMemsetAsync(counts, 0, (size_t)(N_NODES + 784) * sizeof(int), stream);

    bin_hist<<<(N_EDGES + 255) / 256, 256, 0, stream>>>(src, dst, counts, cursor, binned);
    xws_kernel<<<(N_NODES + 15) / 16, 256, 0, stream>>>(x, W, counts, xws, dis);
    gather_out<<<N_BUCKETS, 256, 0, stream>>>(binned, cursor, dis, xws, b, out);
}

// Round 4
// 148.752 us; speedup vs baseline: 2.3971x; 2.3971x over previous
//
#include <hip/hip_runtime.h>
#include <hip/hip_fp16.h>

#define N_NODES 50000
#define N_EDGES 800000
#define D 64
#define FINE_SHIFT 6
#define FINE_NODES 64                              // dst nodes per fine bucket
#define NBUCK ((N_NODES + FINE_NODES - 1) / FINE_NODES)  // 782
#define CAP 1280          // slots/bucket: mean 1024, sigma 32 -> +8 sigma (+ guard)
#define EPB 8192          // edges per partition block
#define NPART ((N_EDGES + EPB - 1) / EPB)          // 98
#define GRPT (CAP / 256)  // gather records per thread = 5

// ---------------------------------------------------------------------------
// Partition: block-staged binning. Each block counting-sorts 8192 edges in
// LDS by fine bucket, reserves space with ONE batched atomic per touched
// bucket (~98 ops/counter total, vs 1000 per-edge), then streams sorted
// records out with adjacent threads writing adjacent addresses (write-
// combinable runs). Record = (dst<<16)|src, both < 2^16.
// ---------------------------------------------------------------------------
__global__ __launch_bounds__(1024) void partition_edges(
    const int* __restrict__ src, const int* __restrict__ dst,
    int* __restrict__ cursor, unsigned int* __restrict__ binned)
{
    __shared__ int hist[NBUCK];
    __shared__ int start_s[NBUCK];
    __shared__ int lcur[NBUCK];
    __shared__ int base_s[NBUCK];
    __shared__ unsigned int staged[EPB];

    int tid = threadIdx.x;
    int eb  = blockIdx.x * EPB;
    int total = N_EDGES - eb; if (total > EPB) total = EPB;

    for (int i = tid; i < NBUCK; i += 1024) hist[i] = 0;
    __syncthreads();

    unsigned int rec[8];
    #pragma unroll
    for (int u = 0; u < 8; ++u) {
        int j = u * 1024 + tid;
        if (j < total) {
            unsigned int t = (unsigned int)dst[eb + j];
            rec[u] = (t << 16) | (unsigned int)src[eb + j];
            atomicAdd(&hist[t >> FINE_SHIFT], 1);
        } else rec[u] = 0xFFFFFFFFu;
    }
    __syncthreads();

    // exclusive scan of hist[0..781] by wave 0 (13 buckets per lane)
    if (tid < 64) {
        int b0 = tid * 13;
        int v[13]; int run = 0;
        #pragma unroll
        for (int j = 0; j < 13; ++j) {
            int idx = b0 + j;
            int c = (idx < NBUCK) ? hist[idx] : 0;
            v[j] = run; run += c;
        }
        int s = run;
        #pragma unroll
        for (int off = 1; off < 64; off <<= 1) {
            int t = __shfl_up(s, off);
            if (tid >= off) s += t;
        }
        int excl = s - run;
        #pragma unroll
        for (int j = 0; j < 13; ++j) {
            int idx = b0 + j;
            if (idx < NBUCK) { start_s[idx] = excl + v[j]; lcur[idx] = excl + v[j]; }
        }
    }
    __syncthreads();

    // batched global reservation (one atomic per touched bucket per block)
    for (int i = tid; i < NBUCK; i += 1024) {
        int c = hist[i];
        base_s[i] = c ? atomicAdd(&cursor[i], c) : 0;
    }
    // LDS scatter into bucket-sorted order (concurrent with reservations)
    #pragma unroll
    for (int u = 0; u < 8; ++u) {
        unsigned int v = rec[u];
        if (v != 0xFFFFFFFFu) {
            int cb = v >> (16 + FINE_SHIFT);
            int p  = atomicAdd(&lcur[cb], 1);
            staged[p] = v;
        }
    }
    __syncthreads();

    // stream out: consecutive threads -> consecutive addresses within runs
    for (int i = tid; i < total; i += 1024) {
        unsigned int v = staged[i];
        int cb = v >> (16 + FINE_SHIFT);
        int gp = base_s[cb] + (i - start_s[cb]);
        if (gp < CAP) binned[(size_t)cb * CAP + gp] = v;
    }
}

// ---------------------------------------------------------------------------
// Per-bucket degree -> dis = rsqrt(deg+1). One block per bucket.
// ---------------------------------------------------------------------------
__global__ __launch_bounds__(128) void bucket_dis(
    const int* __restrict__ cursor, const unsigned int* __restrict__ binned,
    float* __restrict__ dis)
{
    __shared__ int h[FINE_NODES];
    int cb = blockIdx.x, tid = threadIdx.x;
    if (tid < FINE_NODES) h[tid] = 0;
    __syncthreads();
    int cnt = cursor[cb]; if (cnt > CAP) cnt = CAP;
    const unsigned int* br = binned + (size_t)cb * CAP;
    for (int i = tid; i < cnt; i += 128)
        atomicAdd(&h[(br[i] >> 16) & (FINE_NODES - 1)], 1);
    __syncthreads();
    if (tid < FINE_NODES) {
        int n = cb * FINE_NODES + tid;
        if (n < N_NODES) dis[n] = rsqrtf((float)h[tid] + 1.0f);
    }
}

// ---------------------------------------------------------------------------
// xws = dis[row] * (x @ W), stored fp16 (halves gather fetch; err ~5e-4).
// ---------------------------------------------------------------------------
__global__ void xws_kernel(const float* __restrict__ x, const float* __restrict__ W,
                           const float* __restrict__ dis, __half* __restrict__ xwsh)
{
    __shared__ float Ws[D * D];
    __shared__ float xs[4][D];
    int tid = threadIdx.x;
    for (int i = tid; i < D * D; i += 256) Ws[i] = W[i];
    __syncthreads();

    int col = tid & 63;
    int r   = tid >> 6;
    int rowBase = blockIdx.x * 16;

    for (int g = 0; g < 4; ++g) {
        int row = rowBase + g * 4 + r;
        __syncthreads();
        if (row < N_NODES) xs[r][col] = x[row * D + col];
        __syncthreads();
        if (row < N_NODES) {
            float sum = 0.f;
            #pragma unroll
            for (int k = 0; k < D; ++k)
                sum = fmaf(xs[r][k], Ws[k * D + col], sum);
            xwsh[(size_t)row * D + col] = __float2half(dis[row] * sum);
        }
    }
}

// ---------------------------------------------------------------------------
// Gather: one block per bucket. LDS counting-sort of the bucket's records,
// then wave-per-node consumption with 4-deep MLP. lane = feature.
// ---------------------------------------------------------------------------
__global__ __launch_bounds__(256) void gather_out(
    const int* __restrict__ cursor, const unsigned int* __restrict__ binned,
    const float* __restrict__ dis, const __half* __restrict__ xwsh,
    const float* __restrict__ b, float* __restrict__ out)
{
    __shared__ unsigned short ssrc[CAP];
    __shared__ int h[FINE_NODES], off_s[FINE_NODES], cur[FINE_NODES];

    int cb = blockIdx.x, tid = threadIdx.x;
    int wave = tid >> 6, lane = tid & 63;
    int nb = cb * FINE_NODES;
    int cnt = cursor[cb]; if (cnt > CAP) cnt = CAP;
    const unsigned int* br = binned + (size_t)cb * CAP;

    if (tid < FINE_NODES) h[tid] = 0;
    __syncthreads();

    unsigned int rec[GRPT];
    #pragma unroll
    for (int u = 0; u < GRPT; ++u) {
        int j = u * 256 + tid;
        if (j < cnt) {
            unsigned int v = br[j];
            rec[u] = v;
            atomicAdd(&h[(v >> 16) & (FINE_NODES - 1)], 1);
        } else rec[u] = 0xFFFFFFFFu;
    }
    __syncthreads();

    if (tid < 64) {
        int v = h[tid], s = v;
        #pragma unroll
        for (int off = 1; off < 64; off <<= 1) {
            int t = __shfl_up(s, off);
            if (tid >= off) s += t;
        }
        off_s[tid] = s - v;
        cur[tid]   = s - v;
    }
    __syncthreads();

    #pragma unroll
    for (int u = 0; u < GRPT; ++u) {
        unsigned int v = rec[u];
        if (v != 0xFFFFFFFFu) {
            int p = atomicAdd(&cur[(v >> 16) & (FINE_NODES - 1)], 1);
            ssrc[p] = (unsigned short)(v & 0xFFFFu);
        }
    }
    __syncthreads();

    float bl = b[lane];
    for (int i = 0; i < 16; ++i) {
        int nl = wave * 16 + i;
        int n  = nb + nl;
        if (n >= N_NODES) continue;
        int off = off_s[nl], c = h[nl];
        float acc = __half2float(xwsh[(size_t)n * D + lane]);  // self term
        int k = 0;
        for (; k + 3 < c; k += 4) {                            // 4-way MLP
            int s0 = ssrc[off + k], s1 = ssrc[off + k + 1];
            int s2 = ssrc[off + k + 2], s3 = ssrc[off + k + 3];
            float v0 = __half2float(xwsh[(size_t)s0 * D + lane]);
            float v1 = __half2float(xwsh[(size_t)s1 * D + lane]);
            float v2 = __half2float(xwsh[(size_t)s2 * D + lane]);
            float v3 = __half2float(xwsh[(size_t)s3 * D + lane]);
            acc += (v0 + v1) + (v2 + v3);
        }
        for (; k < c; ++k)
            acc += __half2float(xwsh[(size_t)ssrc[off + k] * D + lane]);
        out[(size_t)n * D + lane] = fmaxf(bl + dis[n] * acc, 0.0f);
    }
}

// ---------------------------------------------------------------------------
extern "C" void kernel_launch(void* const* d_in, const int* in_sizes, int n_in,
                              void* d_out, int out_size, void* d_ws, size_t ws_size,
                              hipStream_t stream) {
    const float* x  = (const float*)d_in[0];
    const int*   ei = (const int*)d_in[1];   // [2, E] flat: src then dst
    const float* W  = (const float*)d_in[2];
    const float* b  = (const float*)d_in[3];

    const int* src = ei;
    const int* dst = ei + N_EDGES;
    float* out = (float*)d_out;

    // workspace layout (~10.8 MB)
    __half*       xwsh   = (__half*)d_ws;                        // N*D halves (6.4 MB)
    float*        dis    = (float*)(xwsh + (size_t)N_NODES * D); // N floats
    int*          cursor = (int*)(dis + N_NODES);                // NBUCK ints (pad 784)
    unsigned int* binned = (unsigned int*)(cursor + 784);        // NBUCK*CAP uints (4.0 MB)

    hipMemsetAsync(cursor, 0, 784 * sizeof(int), stream);
    partition_edges<<<NPART, 1024, 0, stream>>>(src, dst, cursor, binned);
    bucket_dis<<<NBUCK, 128, 0, stream>>>(cursor, binned, dis);
    xws_kernel<<<(N_NODES + 15) / 16, 256, 0, stream>>>(x, W, dis, xwsh);
    gather_out<<<NBUCK, 256, 0, stream>>>(cursor, binned, dis, xwsh, b, out);
}

// Round 5
// 120.850 us; speedup vs baseline: 2.9506x; 1.2309x over previous
//
#include <hip/hip_runtime.h>

#define N_NODES 50000
#define N_EDGES 800000
#define D 64
#define FINE_SHIFT 6
#define FINE_NODES 64
#define NBUCK ((N_NODES + FINE_NODES - 1) / FINE_NODES)  // 782
#define CAP 1280
#define EPB 8192
#define NPART ((N_EDGES + EPB - 1) / EPB)                // 98
#define GRPT (CAP / 256)                                 // 5

typedef _Float16 f16;
typedef __attribute__((ext_vector_type(2))) _Float16 f16x2;
typedef __attribute__((ext_vector_type(4))) _Float16 f16x4;
typedef __attribute__((ext_vector_type(8))) _Float16 f16x8;
typedef __attribute__((ext_vector_type(4))) float f32x4;

// ---------------------------------------------------------------------------
// Partition (unchanged from R4): block-staged binning, batched reservations.
// Record = (dst<<16)|src.
// ---------------------------------------------------------------------------
__global__ __launch_bounds__(1024) void partition_edges(
    const int* __restrict__ src, const int* __restrict__ dst,
    int* __restrict__ cursor, unsigned int* __restrict__ binned)
{
    __shared__ int hist[NBUCK];
    __shared__ int start_s[NBUCK];
    __shared__ int lcur[NBUCK];
    __shared__ int base_s[NBUCK];
    __shared__ unsigned int staged[EPB];

    int tid = threadIdx.x;
    int eb  = blockIdx.x * EPB;
    int total = N_EDGES - eb; if (total > EPB) total = EPB;

    for (int i = tid; i < NBUCK; i += 1024) hist[i] = 0;
    __syncthreads();

    unsigned int rec[8];
    #pragma unroll
    for (int u = 0; u < 8; ++u) {
        int j = u * 1024 + tid;
        if (j < total) {
            unsigned int t = (unsigned int)dst[eb + j];
            rec[u] = (t << 16) | (unsigned int)src[eb + j];
            atomicAdd(&hist[t >> FINE_SHIFT], 1);
        } else rec[u] = 0xFFFFFFFFu;
    }
    __syncthreads();

    if (tid < 64) {
        int b0 = tid * 13;
        int v[13]; int run = 0;
        #pragma unroll
        for (int j = 0; j < 13; ++j) {
            int idx = b0 + j;
            int c = (idx < NBUCK) ? hist[idx] : 0;
            v[j] = run; run += c;
        }
        int s = run;
        #pragma unroll
        for (int off = 1; off < 64; off <<= 1) {
            int t = __shfl_up(s, off);
            if (tid >= off) s += t;
        }
        int excl = s - run;
        #pragma unroll
        for (int j = 0; j < 13; ++j) {
            int idx = b0 + j;
            if (idx < NBUCK) { start_s[idx] = excl + v[j]; lcur[idx] = excl + v[j]; }
        }
    }
    __syncthreads();

    for (int i = tid; i < NBUCK; i += 1024) {
        int c = hist[i];
        base_s[i] = c ? atomicAdd(&cursor[i], c) : 0;
    }
    #pragma unroll
    for (int u = 0; u < 8; ++u) {
        unsigned int v = rec[u];
        if (v != 0xFFFFFFFFu) {
            int cb = v >> (16 + FINE_SHIFT);
            int p  = atomicAdd(&lcur[cb], 1);
            staged[p] = v;
        }
    }
    __syncthreads();

    for (int i = tid; i < total; i += 1024) {
        unsigned int v = staged[i];
        int cb = v >> (16 + FINE_SHIFT);
        int gp = base_s[cb] + (i - start_s[cb]);
        if (gp < CAP) binned[(size_t)cb * CAP + gp] = v;
    }
}

// ---------------------------------------------------------------------------
// Fused: per-bucket degree->dis (LDS) + xws = dis*(x@W) via fp16 MFMA.
// One block per bucket (64 rows). Row-padded LDS tiles (72 halves = 144B,
// 16B-aligned, <=2-way banked). A[m=lane&15][k=(lane>>4)*8+j] fragments.
// ---------------------------------------------------------------------------
__global__ __launch_bounds__(256) void xws_fused(
    const int* __restrict__ cursor, const unsigned int* __restrict__ binned,
    const float* __restrict__ x, const float* __restrict__ W,
    f16* __restrict__ xwsh)
{
    __shared__ f16 xsH[64][72];
    __shared__ f16 WtH[64][72];
    __shared__ float dis_l[64];
    __shared__ int h[64];

    int bu = blockIdx.x, tid = threadIdx.x;
    int nb = bu * FINE_NODES;

    if (tid < 64) h[tid] = 0;
    __syncthreads();
    int cnt = cursor[bu]; if (cnt > CAP) cnt = CAP;
    const unsigned int* br = binned + (size_t)bu * CAP;
    for (int i = tid; i < cnt; i += 256)
        atomicAdd(&h[(br[i] >> 16) & 63], 1);

    // stage x rows nb..nb+63 as fp16
    const float4* x4 = (const float4*)x;
    for (int j = tid; j < 1024; j += 256) {
        int row = j >> 4, c4 = (j & 15) * 4;
        float4 v;
        if (nb + row < N_NODES) v = x4[(size_t)(nb + row) * 16 + (j & 15)];
        else { v.x = v.y = v.z = v.w = 0.f; }
        f16x4 hv = { (f16)v.x, (f16)v.y, (f16)v.z, (f16)v.w };
        *(f16x4*)&xsH[row][c4] = hv;
    }
    // stage W transposed as fp16: WtH[n][k] = W[k*64+n]
    for (int j = tid; j < 4096; j += 256) {
        int k = j >> 6, n = j & 63;
        WtH[n][k] = (f16)W[j];
    }
    __syncthreads();
    if (tid < 64) dis_l[tid] = rsqrtf((float)h[tid] + 1.0f);
    __syncthreads();

    int wave = tid >> 6, lane = tid & 63;
    int m = lane & 15, q = lane >> 4;

    f16x8 a0 = *(const f16x8*)&xsH[wave * 16 + m][q * 8];
    f16x8 a1 = *(const f16x8*)&xsH[wave * 16 + m][32 + q * 8];

    f32x4 acc[4];
    #pragma unroll
    for (int t = 0; t < 4; ++t) {
        int n0 = t * 16;
        f16x8 b0 = *(const f16x8*)&WtH[n0 + m][q * 8];
        f16x8 b1 = *(const f16x8*)&WtH[n0 + m][32 + q * 8];
        f32x4 z = { 0.f, 0.f, 0.f, 0.f };
        z = __builtin_amdgcn_mfma_f32_16x16x32_f16(a0, b0, z, 0, 0, 0);
        acc[t] = __builtin_amdgcn_mfma_f32_16x16x32_f16(a1, b1, z, 0, 0, 0);
    }

    // epilogue: scale rows by dis, fp16, park in xsH (wave-private rows)
    #pragma unroll
    for (int t = 0; t < 4; ++t) {
        int n0 = t * 16;
        #pragma unroll
        for (int r = 0; r < 4; ++r) {
            int row = q * 4 + r;
            xsH[wave * 16 + row][n0 + m] = (f16)(acc[t][r] * dis_l[wave * 16 + row]);
        }
    }
    __syncthreads();

    for (int j = tid; j < 512; j += 256) {
        int row = j >> 3, seg = (j & 7) * 8;
        if (nb + row < N_NODES)
            *(f16x8*)&xwsh[(size_t)(nb + row) * D + seg] = *(const f16x8*)&xsH[row][seg];
    }
}

// ---------------------------------------------------------------------------
// Gather: per-bucket LDS counting-sort, then wave-per-node with half2
// feature pairs: lanes 0-31 even records, 32-63 odd records (256B/load,
// 8 rows in flight). dis recomputed from local histogram.
// ---------------------------------------------------------------------------
__global__ __launch_bounds__(256) void gather_out(
    const int* __restrict__ cursor, const unsigned int* __restrict__ binned,
    const f16* __restrict__ xwsh, const float* __restrict__ b,
    float* __restrict__ out)
{
    __shared__ unsigned short ssrc[CAP];
    __shared__ int h[64], off_s[64], cur[64];

    int cb = blockIdx.x, tid = threadIdx.x;
    int wave = tid >> 6, lane = tid & 63;
    int nb = cb * FINE_NODES;
    int cnt = cursor[cb]; if (cnt > CAP) cnt = CAP;
    const unsigned int* br = binned + (size_t)cb * CAP;

    if (tid < 64) h[tid] = 0;
    __syncthreads();

    unsigned int rec[GRPT];
    #pragma unroll
    for (int u = 0; u < GRPT; ++u) {
        int j = u * 256 + tid;
        if (j < cnt) {
            rec[u] = br[j];
            atomicAdd(&h[(rec[u] >> 16) & 63], 1);
        } else rec[u] = 0xFFFFFFFFu;
    }
    __syncthreads();

    if (tid < 64) {
        int v = h[tid], s = v;
        #pragma unroll
        for (int off = 1; off < 64; off <<= 1) {
            int t = __shfl_up(s, off);
            if (tid >= off) s += t;
        }
        off_s[tid] = s - v;
        cur[tid]   = s - v;
    }
    __syncthreads();

    #pragma unroll
    for (int u = 0; u < GRPT; ++u) {
        unsigned int v = rec[u];
        if (v != 0xFFFFFFFFu) {
            int p = atomicAdd(&cur[(v >> 16) & 63], 1);
            ssrc[p] = (unsigned short)(v & 0xFFFFu);
        }
    }
    __syncthreads();

    const f16x2* xw2 = (const f16x2*)xwsh;   // row i = 32 f16x2
    float2* out2 = (float2*)out;             // row i = 32 float2
    int c32 = lane & 31;
    int hid = lane >> 5;
    float2 bl2 = ((const float2*)b)[c32];

    for (int i = 0; i < 16; ++i) {
        int nl = wave * 16 + i;
        int n  = nb + nl;
        if (n >= N_NODES) break;             // wave-uniform
        int off = off_s[nl], c = h[nl];
        float dn = rsqrtf((float)c + 1.0f);

        float2 acc; acc.x = 0.f; acc.y = 0.f;
        if (hid == 0) {
            f16x2 sv = xw2[(size_t)n * 32 + c32];   // self term
            acc.x = (float)sv.x; acc.y = (float)sv.y;
        }
        int k = off + hid, e = off + c;
        for (; k + 6 < e; k += 8) {
            int s0 = ssrc[k], s1 = ssrc[k + 2], s2 = ssrc[k + 4], s3 = ssrc[k + 6];
            f16x2 v0 = xw2[(size_t)s0 * 32 + c32];
            f16x2 v1 = xw2[(size_t)s1 * 32 + c32];
            f16x2 v2 = xw2[(size_t)s2 * 32 + c32];
            f16x2 v3 = xw2[(size_t)s3 * 32 + c32];
            acc.x += ((float)v0.x + (float)v1.x) + ((float)v2.x + (float)v3.x);
            acc.y += ((float)v0.y + (float)v1.y) + ((float)v2.y + (float)v3.y);
        }
        for (; k < e; k += 2) {
            f16x2 v = xw2[(size_t)ssrc[k] * 32 + c32];
            acc.x += (float)v.x; acc.y += (float)v.y;
        }
        acc.x += __shfl(acc.x, lane + 32);   // fold hi half into lo
        acc.y += __shfl(acc.y, lane + 32);
        if (hid == 0) {
            float2 r;
            r.x = fmaxf(bl2.x + dn * acc.x, 0.f);
            r.y = fmaxf(bl2.y + dn * acc.y, 0.f);
            out2[(size_t)n * 32 + c32] = r;
        }
    }
}

// ---------------------------------------------------------------------------
extern "C" void kernel_launch(void* const* d_in, const int* in_sizes, int n_in,
                              void* d_out, int out_size, void* d_ws, size_t ws_size,
                              hipStream_t stream) {
    const float* x  = (const float*)d_in[0];
    const int*   ei = (const int*)d_in[1];   // [2, E] flat: src then dst
    const float* W  = (const float*)d_in[2];
    const float* b  = (const float*)d_in[3];

    const int* src = ei;
    const int* dst = ei + N_EDGES;
    float* out = (float*)d_out;

    // workspace: xwsh (6.4 MB) | cursor (784 ints) | binned (4.0 MB)
    f16*          xwsh   = (f16*)d_ws;
    int*          cursor = (int*)(xwsh + (size_t)N_NODES * D);
    unsigned int* binned = (unsigned int*)(cursor + 784);

    hipMemsetAsync(cursor, 0, 784 * sizeof(int), stream);
    partition_edges<<<NPART, 1024, 0, stream>>>(src, dst, cursor, binned);
    xws_fused<<<NBUCK, 256, 0, stream>>>(cursor, binned, x, W, xwsh);
    gather_out<<<NBUCK, 256, 0, stream>>>(cursor, binned, xwsh, b, out);
}

// Round 6
// 120.461 us; speedup vs baseline: 2.9601x; 1.0032x over previous
//
#include <hip/hip_runtime.h>

#define N_NODES 50000
#define N_EDGES 800000
#define D 64
#define FINE_SHIFT 6
#define FINE_NODES 64
#define NBUCK ((N_NODES + FINE_NODES - 1) / FINE_NODES)  // 782
#define CAP 1280
#define EPB 4096
#define NPART ((N_EDGES + EPB - 1) / EPB)                // 196
#define GRPT (CAP / 256)                                 // 5

typedef _Float16 f16;
typedef __attribute__((ext_vector_type(2))) _Float16 f16x2;
typedef __attribute__((ext_vector_type(8))) _Float16 f16x8;
typedef __attribute__((ext_vector_type(4))) float f32x4;

// ---------------------------------------------------------------------------
// Partition: block-staged binning (EPB=4096, 196 blocks for ~2x CU coverage
// vs 98). Block 0 additionally precomputes fp16 W-transpose into global
// (shared by all xws_fused blocks). Record = (dst<<16)|src.
// ---------------------------------------------------------------------------
__global__ __launch_bounds__(1024) void partition_edges(
    const int* __restrict__ src, const int* __restrict__ dst,
    int* __restrict__ cursor, unsigned int* __restrict__ binned,
    const float* __restrict__ W, f16* __restrict__ Wt16)
{
    __shared__ int hist[NBUCK];
    __shared__ int start_s[NBUCK];
    __shared__ int lcur[NBUCK];
    __shared__ int base_s[NBUCK];
    __shared__ unsigned int staged[EPB];

    int tid = threadIdx.x;
    int eb  = blockIdx.x * EPB;
    int total = N_EDGES - eb; if (total > EPB) total = EPB;

    // block 0: one-time Wt16[n*64+k] = fp16(W[k*64+n])
    if (blockIdx.x == 0) {
        for (int j = tid; j < 4096; j += 1024) {
            int n = j >> 6, k = j & 63;
            Wt16[j] = (f16)W[k * 64 + n];
        }
    }

    for (int i = tid; i < NBUCK; i += 1024) hist[i] = 0;
    __syncthreads();

    unsigned int rec[4];
    #pragma unroll
    for (int u = 0; u < 4; ++u) {
        int j = u * 1024 + tid;
        if (j < total) {
            unsigned int t = (unsigned int)dst[eb + j];
            rec[u] = (t << 16) | (unsigned int)src[eb + j];
            atomicAdd(&hist[t >> FINE_SHIFT], 1);
        } else rec[u] = 0xFFFFFFFFu;
    }
    __syncthreads();

    // exclusive scan of hist[0..781] by wave 0 (13 buckets per lane)
    if (tid < 64) {
        int b0 = tid * 13;
        int v[13]; int run = 0;
        #pragma unroll
        for (int j = 0; j < 13; ++j) {
            int idx = b0 + j;
            int c = (idx < NBUCK) ? hist[idx] : 0;
            v[j] = run; run += c;
        }
        int s = run;
        #pragma unroll
        for (int off = 1; off < 64; off <<= 1) {
            int t = __shfl_up(s, off);
            if (tid >= off) s += t;
        }
        int excl = s - run;
        #pragma unroll
        for (int j = 0; j < 13; ++j) {
            int idx = b0 + j;
            if (idx < NBUCK) { start_s[idx] = excl + v[j]; lcur[idx] = excl + v[j]; }
        }
    }
    __syncthreads();

    // batched global reservation (one atomic per touched bucket per block)
    for (int i = tid; i < NBUCK; i += 1024) {
        int c = hist[i];
        base_s[i] = c ? atomicAdd(&cursor[i], c) : 0;
    }
    // LDS scatter into bucket-sorted order
    #pragma unroll
    for (int u = 0; u < 4; ++u) {
        unsigned int v = rec[u];
        if (v != 0xFFFFFFFFu) {
            int cb = v >> (16 + FINE_SHIFT);
            int p  = atomicAdd(&lcur[cb], 1);
            staged[p] = v;
        }
    }
    __syncthreads();

    // stream out: consecutive threads -> consecutive addresses within runs
    for (int i = tid; i < total; i += 1024) {
        unsigned int v = staged[i];
        int cb = v >> (16 + FINE_SHIFT);
        int gp = base_s[cb] + (i - start_s[cb]);
        if (gp < CAP) binned[(size_t)cb * CAP + gp] = v;
    }
}

// ---------------------------------------------------------------------------
// Fused degree+xws, lean version: A-fragments loaded directly from global x
// (no x LDS tile), Wt staged from precomputed global fp16 Wt16 with 2
// vectorized copies/thread (no 4096-scalar transpose). 18.7KB LDS -> high
// occupancy for latency hiding.
// ---------------------------------------------------------------------------
__global__ __launch_bounds__(256) void xws_fused(
    const int* __restrict__ cursor, const unsigned int* __restrict__ binned,
    const float* __restrict__ x, const f16* __restrict__ Wt16,
    f16* __restrict__ xwsh)
{
    __shared__ f16 WtH[64][72];
    __shared__ f16 park[64][72];
    __shared__ int h[64];

    int bu = blockIdx.x, tid = threadIdx.x;
    int nb = bu * FINE_NODES;

    if (tid < 64) h[tid] = 0;
    __syncthreads();

    // degree histogram from binned records
    int cnt = cursor[bu]; if (cnt > CAP) cnt = CAP;
    const unsigned int* br = binned + (size_t)bu * CAP;
    for (int i = tid; i < cnt; i += 256)
        atomicAdd(&h[(br[i] >> 16) & 63], 1);

    // stage Wt (B-operand layout: WtH[n][k]) — vectorized f16x8 copies
    for (int j = tid; j < 512; j += 256) {
        int row = j >> 3, seg = (j & 7) * 8;
        *(f16x8*)&WtH[row][seg] = *(const f16x8*)&Wt16[row * 64 + seg];
    }
    __syncthreads();

    int wave = tid >> 6, lane = tid & 63;
    int m = lane & 15, q = lane >> 4;

    // A fragments straight from global x (rows nb+wave*16+m, k=q*8..)
    int ar = nb + wave * 16 + m;
    if (ar >= N_NODES) ar = N_NODES - 1;   // clamped; outputs guarded at store
    const float4* x4 = (const float4*)x;
    size_t rb = (size_t)ar * 16;
    float4 p0 = x4[rb + q * 2];
    float4 p1 = x4[rb + q * 2 + 1];
    float4 p2 = x4[rb + 8 + q * 2];
    float4 p3 = x4[rb + 8 + q * 2 + 1];
    f16x8 a0 = { (f16)p0.x, (f16)p0.y, (f16)p0.z, (f16)p0.w,
                 (f16)p1.x, (f16)p1.y, (f16)p1.z, (f16)p1.w };
    f16x8 a1 = { (f16)p2.x, (f16)p2.y, (f16)p2.z, (f16)p2.w,
                 (f16)p3.x, (f16)p3.y, (f16)p3.z, (f16)p3.w };

    f32x4 acc[4];
    #pragma unroll
    for (int t = 0; t < 4; ++t) {
        int n0 = t * 16;
        f16x8 b0 = *(const f16x8*)&WtH[n0 + m][q * 8];
        f16x8 b1 = *(const f16x8*)&WtH[n0 + m][32 + q * 8];
        f32x4 z = { 0.f, 0.f, 0.f, 0.f };
        z = __builtin_amdgcn_mfma_f32_16x16x32_f16(a0, b0, z, 0, 0, 0);
        acc[t] = __builtin_amdgcn_mfma_f32_16x16x32_f16(a1, b1, z, 0, 0, 0);
    }

    // scale rows by dis = rsqrt(deg+1), park as fp16
    float disr[4];
    #pragma unroll
    for (int r = 0; r < 4; ++r)
        disr[r] = rsqrtf((float)h[wave * 16 + q * 4 + r] + 1.0f);
    #pragma unroll
    for (int t = 0; t < 4; ++t) {
        int n0 = t * 16;
        #pragma unroll
        for (int r = 0; r < 4; ++r)
            park[wave * 16 + q * 4 + r][n0 + m] = (f16)(acc[t][r] * disr[r]);
    }
    __syncthreads();

    for (int j = tid; j < 512; j += 256) {
        int row = j >> 3, seg = (j & 7) * 8;
        if (nb + row < N_NODES)
            *(f16x8*)&xwsh[(size_t)(nb + row) * D + seg] = *(const f16x8*)&park[row][seg];
    }
}

// ---------------------------------------------------------------------------
// Gather (unchanged from R5): per-bucket LDS counting-sort, wave-per-node,
// half2 feature pairs (lanes 0-31 even records, 32-63 odd).
// ---------------------------------------------------------------------------
__global__ __launch_bounds__(256) void gather_out(
    const int* __restrict__ cursor, const unsigned int* __restrict__ binned,
    const f16* __restrict__ xwsh, const float* __restrict__ b,
    float* __restrict__ out)
{
    __shared__ unsigned short ssrc[CAP];
    __shared__ int h[64], off_s[64], cur[64];

    int cb = blockIdx.x, tid = threadIdx.x;
    int wave = tid >> 6, lane = tid & 63;
    int nb = cb * FINE_NODES;
    int cnt = cursor[cb]; if (cnt > CAP) cnt = CAP;
    const unsigned int* br = binned + (size_t)cb * CAP;

    if (tid < 64) h[tid] = 0;
    __syncthreads();

    unsigned int rec[GRPT];
    #pragma unroll
    for (int u = 0; u < GRPT; ++u) {
        int j = u * 256 + tid;
        if (j < cnt) {
            rec[u] = br[j];
            atomicAdd(&h[(rec[u] >> 16) & 63], 1);
        } else rec[u] = 0xFFFFFFFFu;
    }
    __syncthreads();

    if (tid < 64) {
        int v = h[tid], s = v;
        #pragma unroll
        for (int off = 1; off < 64; off <<= 1) {
            int t = __shfl_up(s, off);
            if (tid >= off) s += t;
        }
        off_s[tid] = s - v;
        cur[tid]   = s - v;
    }
    __syncthreads();

    #pragma unroll
    for (int u = 0; u < GRPT; ++u) {
        unsigned int v = rec[u];
        if (v != 0xFFFFFFFFu) {
            int p = atomicAdd(&cur[(v >> 16) & 63], 1);
            ssrc[p] = (unsigned short)(v & 0xFFFFu);
        }
    }
    __syncthreads();

    const f16x2* xw2 = (const f16x2*)xwsh;   // row i = 32 f16x2
    float2* out2 = (float2*)out;             // row i = 32 float2
    int c32 = lane & 31;
    int hid = lane >> 5;
    float2 bl2 = ((const float2*)b)[c32];

    for (int i = 0; i < 16; ++i) {
        int nl = wave * 16 + i;
        int n  = nb + nl;
        if (n >= N_NODES) break;             // wave-uniform
        int off = off_s[nl], c = h[nl];
        float dn = rsqrtf((float)c + 1.0f);

        float2 acc; acc.x = 0.f; acc.y = 0.f;
        if (hid == 0) {
            f16x2 sv = xw2[(size_t)n * 32 + c32];   // self term
            acc.x = (float)sv.x; acc.y = (float)sv.y;
        }
        int k = off + hid, e = off + c;
        for (; k + 6 < e; k += 8) {
            int s0 = ssrc[k], s1 = ssrc[k + 2], s2 = ssrc[k + 4], s3 = ssrc[k + 6];
            f16x2 v0 = xw2[(size_t)s0 * 32 + c32];
            f16x2 v1 = xw2[(size_t)s1 * 32 + c32];
            f16x2 v2 = xw2[(size_t)s2 * 32 + c32];
            f16x2 v3 = xw2[(size_t)s3 * 32 + c32];
            acc.x += ((float)v0.x + (float)v1.x) + ((float)v2.x + (float)v3.x);
            acc.y += ((float)v0.y + (float)v1.y) + ((float)v2.y + (float)v3.y);
        }
        for (; k < e; k += 2) {
            f16x2 v = xw2[(size_t)ssrc[k] * 32 + c32];
            acc.x += (float)v.x; acc.y += (float)v.y;
        }
        acc.x += __shfl(acc.x, lane + 32);   // fold hi half into lo
        acc.y += __shfl(acc.y, lane + 32);
        if (hid == 0) {
            float2 r;
            r.x = fmaxf(bl2.x + dn * acc.x, 0.f);
            r.y = fmaxf(bl2.y + dn * acc.y, 0.f);
            out2[(size_t)n * 32 + c32] = r;
        }
    }
}

// ---------------------------------------------------------------------------
extern "C" void kernel_launch(void* const* d_in, const int* in_sizes, int n_in,
                              void* d_out, int out_size, void* d_ws, size_t ws_size,
                              hipStream_t stream) {
    const float* x  = (const float*)d_in[0];
    const int*   ei = (const int*)d_in[1];   // [2, E] flat: src then dst
    const float* W  = (const float*)d_in[2];
    const float* b  = (const float*)d_in[3];

    const int* src = ei;
    const int* dst = ei + N_EDGES;
    float* out = (float*)d_out;

    // workspace: xwsh (6.4MB) | cursor (784 ints) | binned (4.0MB) | Wt16 (8KB)
    f16*          xwsh   = (f16*)d_ws;
    int*          cursor = (int*)(xwsh + (size_t)N_NODES * D);
    unsigned int* binned = (unsigned int*)(cursor + 784);
    f16*          Wt16   = (f16*)(binned + (size_t)NBUCK * CAP);

    hipMemsetAsync(cursor, 0, 784 * sizeof(int), stream);
    partition_edges<<<NPART, 1024, 0, stream>>>(src, dst, cursor, binned, W, Wt16);
    xws_fused<<<NBUCK, 256, 0, stream>>>(cursor, binned, x, Wt16, xwsh);
    gather_out<<<NBUCK, 256, 0, stream>>>(cursor, binned, xwsh, b, out);
}

// Round 7
// 109.636 us; speedup vs baseline: 3.2523x; 1.0987x over previous
//
#include <hip/hip_runtime.h>

#define N_NODES 50000
#define N_EDGES 800000
#define D 64
#define FINE_SHIFT 6
#define FINE_NODES 64
#define NBUCK ((N_NODES + FINE_NODES - 1) / FINE_NODES)  // 782
#define CAP 1280
#define EPB 8192
#define NPART ((N_EDGES + EPB - 1) / EPB)                // 98
#define CSTRIDE 16                                       // cursor pad: 1 per 64B line

typedef _Float16 f16;
typedef __attribute__((ext_vector_type(4))) _Float16 f16x4;
typedef __attribute__((ext_vector_type(8))) _Float16 f16x8;
typedef __attribute__((ext_vector_type(4))) float f32x4;

// ---------------------------------------------------------------------------
// Partition: block-staged binning. EPB=8192 (98 blocks, fewest reservation
// atomics); cursors padded one-per-cache-line (no false sharing); edge loads
// vectorized int4 (8 consecutive edges per thread). Record = (dst<<16)|src.
// Block 0 also precomputes fp16 W-transpose for xws_fused.
// ---------------------------------------------------------------------------
__global__ __launch_bounds__(1024) void partition_edges(
    const int* __restrict__ src, const int* __restrict__ dst,
    int* __restrict__ cursor, unsigned int* __restrict__ binned,
    const float* __restrict__ W, f16* __restrict__ Wt16)
{
    __shared__ int hist[NBUCK];
    __shared__ int start_s[NBUCK];
    __shared__ int lcur[NBUCK];
    __shared__ int base_s[NBUCK];
    __shared__ unsigned int staged[EPB];

    int tid = threadIdx.x;
    int eb  = blockIdx.x * EPB;
    int total = N_EDGES - eb; if (total > EPB) total = EPB;  // 8192 or 5376 (both %8==0)

    if (blockIdx.x == 0) {  // one-time Wt16[n*64+k] = fp16(W[k*64+n])
        for (int j = tid; j < 4096; j += 1024) {
            int n = j >> 6, k = j & 63;
            Wt16[j] = (f16)W[k * 64 + n];
        }
    }

    for (int i = tid; i < NBUCK; i += 1024) hist[i] = 0;
    __syncthreads();

    unsigned int rec[8];
    int jb = tid * 8;
    if (jb < total) {
        int4 s0 = *(const int4*)&src[eb + jb];
        int4 s1 = *(const int4*)&src[eb + jb + 4];
        int4 d0 = *(const int4*)&dst[eb + jb];
        int4 d1 = *(const int4*)&dst[eb + jb + 4];
        rec[0] = ((unsigned)d0.x << 16) | (unsigned)s0.x;
        rec[1] = ((unsigned)d0.y << 16) | (unsigned)s0.y;
        rec[2] = ((unsigned)d0.z << 16) | (unsigned)s0.z;
        rec[3] = ((unsigned)d0.w << 16) | (unsigned)s0.w;
        rec[4] = ((unsigned)d1.x << 16) | (unsigned)s1.x;
        rec[5] = ((unsigned)d1.y << 16) | (unsigned)s1.y;
        rec[6] = ((unsigned)d1.z << 16) | (unsigned)s1.z;
        rec[7] = ((unsigned)d1.w << 16) | (unsigned)s1.w;
        #pragma unroll
        for (int u = 0; u < 8; ++u)
            atomicAdd(&hist[rec[u] >> (16 + FINE_SHIFT)], 1);
    } else {
        #pragma unroll
        for (int u = 0; u < 8; ++u) rec[u] = 0xFFFFFFFFu;
    }
    __syncthreads();

    // exclusive scan of hist[0..781] by wave 0 (13 buckets per lane)
    if (tid < 64) {
        int b0 = tid * 13;
        int v[13]; int run = 0;
        #pragma unroll
        for (int j = 0; j < 13; ++j) {
            int idx = b0 + j;
            int c = (idx < NBUCK) ? hist[idx] : 0;
            v[j] = run; run += c;
        }
        int s = run;
        #pragma unroll
        for (int off = 1; off < 64; off <<= 1) {
            int t = __shfl_up(s, off);
            if (tid >= off) s += t;
        }
        int excl = s - run;
        #pragma unroll
        for (int j = 0; j < 13; ++j) {
            int idx = b0 + j;
            if (idx < NBUCK) { start_s[idx] = excl + v[j]; lcur[idx] = excl + v[j]; }
        }
    }
    __syncthreads();

    // batched global reservation — one padded counter per cache line
    for (int i = tid; i < NBUCK; i += 1024) {
        int c = hist[i];
        base_s[i] = c ? atomicAdd(&cursor[i * CSTRIDE], c) : 0;
    }
    // LDS scatter into bucket-sorted order
    #pragma unroll
    for (int u = 0; u < 8; ++u) {
        unsigned int v = rec[u];
        if (v != 0xFFFFFFFFu) {
            int cb = v >> (16 + FINE_SHIFT);
            int p  = atomicAdd(&lcur[cb], 1);
            staged[p] = v;
        }
    }
    __syncthreads();

    // stream out: consecutive threads -> consecutive addresses within runs
    for (int i = tid; i < total; i += 1024) {
        unsigned int v = staged[i];
        int cb = v >> (16 + FINE_SHIFT);
        int gp = base_s[cb] + (i - start_s[cb]);
        if (gp < CAP) binned[(size_t)cb * CAP + gp] = v;
    }
}

// ---------------------------------------------------------------------------
// Fused degree+xws (unchanged from R6): A-fragments direct from global x,
// Wt staged from precomputed fp16 Wt16, 16x16x32 fp16 MFMA, dis folded in.
// ---------------------------------------------------------------------------
__global__ __launch_bounds__(256) void xws_fused(
    const int* __restrict__ cursor, const unsigned int* __restrict__ binned,
    const float* __restrict__ x, const f16* __restrict__ Wt16,
    f16* __restrict__ xwsh)
{
    __shared__ f16 WtH[64][72];
    __shared__ f16 park[64][72];
    __shared__ int h[64];

    int bu = blockIdx.x, tid = threadIdx.x;
    int nb = bu * FINE_NODES;

    if (tid < 64) h[tid] = 0;
    __syncthreads();

    int cnt = cursor[bu * CSTRIDE]; if (cnt > CAP) cnt = CAP;
    const unsigned int* br = binned + (size_t)bu * CAP;
    for (int i = tid; i < cnt; i += 256)
        atomicAdd(&h[(br[i] >> 16) & 63], 1);

    for (int j = tid; j < 512; j += 256) {
        int row = j >> 3, seg = (j & 7) * 8;
        *(f16x8*)&WtH[row][seg] = *(const f16x8*)&Wt16[row * 64 + seg];
    }
    __syncthreads();

    int wave = tid >> 6, lane = tid & 63;
    int m = lane & 15, q = lane >> 4;

    int ar = nb + wave * 16 + m;
    if (ar >= N_NODES) ar = N_NODES - 1;   // clamped; stores guarded
    const float4* x4 = (const float4*)x;
    size_t rb = (size_t)ar * 16;
    float4 p0 = x4[rb + q * 2];
    float4 p1 = x4[rb + q * 2 + 1];
    float4 p2 = x4[rb + 8 + q * 2];
    float4 p3 = x4[rb + 8 + q * 2 + 1];
    f16x8 a0 = { (f16)p0.x, (f16)p0.y, (f16)p0.z, (f16)p0.w,
                 (f16)p1.x, (f16)p1.y, (f16)p1.z, (f16)p1.w };
    f16x8 a1 = { (f16)p2.x, (f16)p2.y, (f16)p2.z, (f16)p2.w,
                 (f16)p3.x, (f16)p3.y, (f16)p3.z, (f16)p3.w };

    f32x4 acc[4];
    #pragma unroll
    for (int t = 0; t < 4; ++t) {
        int n0 = t * 16;
        f16x8 b0 = *(const f16x8*)&WtH[n0 + m][q * 8];
        f16x8 b1 = *(const f16x8*)&WtH[n0 + m][32 + q * 8];
        f32x4 z = { 0.f, 0.f, 0.f, 0.f };
        z = __builtin_amdgcn_mfma_f32_16x16x32_f16(a0, b0, z, 0, 0, 0);
        acc[t] = __builtin_amdgcn_mfma_f32_16x16x32_f16(a1, b1, z, 0, 0, 0);
    }

    float disr[4];
    #pragma unroll
    for (int r = 0; r < 4; ++r)
        disr[r] = rsqrtf((float)h[wave * 16 + q * 4 + r] + 1.0f);
    #pragma unroll
    for (int t = 0; t < 4; ++t) {
        int n0 = t * 16;
        #pragma unroll
        for (int r = 0; r < 4; ++r)
            park[wave * 16 + q * 4 + r][n0 + m] = (f16)(acc[t][r] * disr[r]);
    }
    __syncthreads();

    for (int j = tid; j < 512; j += 256) {
        int row = j >> 3, seg = (j & 7) * 8;
        if (nb + row < N_NODES)
            *(f16x8*)&xwsh[(size_t)(nb + row) * D + seg] = *(const f16x8*)&park[row][seg];
    }
}

// ---------------------------------------------------------------------------
// Gather v3: 512 threads/block (8 waves -> ~6 waves/SIMD occupancy), LDS
// counting-sort, then wave-per-node with f16x4 feature chunks: 16 lanes per
// record, 4 records in flight per issue (8 with 2-deep unroll). Fold across
// the 4 lane-groups with shfl_xor(32),(16); coalesced float4 stores.
// ---------------------------------------------------------------------------
__global__ __launch_bounds__(512) void gather_out(
    const int* __restrict__ cursor, const unsigned int* __restrict__ binned,
    const f16* __restrict__ xwsh, const float* __restrict__ b,
    float* __restrict__ out)
{
    __shared__ unsigned short ssrc[CAP];
    __shared__ int h[64], off_s[64], cur[64];

    int cb = blockIdx.x, tid = threadIdx.x;
    int wave = tid >> 6, lane = tid & 63;
    int nb = cb * FINE_NODES;
    int cnt = cursor[cb * CSTRIDE]; if (cnt > CAP) cnt = CAP;
    const unsigned int* br = binned + (size_t)cb * CAP;

    if (tid < 64) h[tid] = 0;
    __syncthreads();

    unsigned int rec[3];
    #pragma unroll
    for (int u = 0; u < 3; ++u) {
        int j = u * 512 + tid;
        if (j < cnt) {
            rec[u] = br[j];
            atomicAdd(&h[(rec[u] >> 16) & 63], 1);
        } else rec[u] = 0xFFFFFFFFu;
    }
    __syncthreads();

    if (tid < 64) {
        int v = h[tid], s = v;
        #pragma unroll
        for (int off = 1; off < 64; off <<= 1) {
            int t = __shfl_up(s, off);
            if (tid >= off) s += t;
        }
        off_s[tid] = s - v;
        cur[tid]   = s - v;
    }
    __syncthreads();

    #pragma unroll
    for (int u = 0; u < 3; ++u) {
        unsigned int v = rec[u];
        if (v != 0xFFFFFFFFu) {
            int p = atomicAdd(&cur[(v >> 16) & 63], 1);
            ssrc[p] = (unsigned short)(v & 0xFFFFu);
        }
    }
    __syncthreads();

    const f16x4* xw4 = (const f16x4*)xwsh;     // row = 16 x f16x4
    const float4* b4p = (const float4*)b;
    float4* out4 = (float4*)out;               // row = 16 x float4
    int g = lane >> 4, c16 = lane & 15;

    for (int i = 0; i < 8; ++i) {
        int nl = wave * 8 + i;
        int n  = nb + nl;
        if (n >= N_NODES) break;               // wave-uniform
        int off = off_s[nl], c = h[nl];

        float a0 = 0.f, a1 = 0.f, a2 = 0.f, a3 = 0.f;
        if (g == 0) {                          // self term
            f16x4 sv = xw4[(size_t)n * 16 + c16];
            a0 = (float)sv.x; a1 = (float)sv.y; a2 = (float)sv.z; a3 = (float)sv.w;
        }
        int k = off + g, e = off + c;
        for (; k + 4 < e; k += 8) {            // 2 records per group in flight
            int s0 = ssrc[k], s1 = ssrc[k + 4];
            f16x4 v0 = xw4[(size_t)s0 * 16 + c16];
            f16x4 v1 = xw4[(size_t)s1 * 16 + c16];
            a0 += (float)v0.x + (float)v1.x;
            a1 += (float)v0.y + (float)v1.y;
            a2 += (float)v0.z + (float)v1.z;
            a3 += (float)v0.w + (float)v1.w;
        }
        if (k < e) {
            f16x4 v = xw4[(size_t)ssrc[k] * 16 + c16];
            a0 += (float)v.x; a1 += (float)v.y; a2 += (float)v.z; a3 += (float)v.w;
        }
        a0 += __shfl_xor(a0, 32); a1 += __shfl_xor(a1, 32);
        a2 += __shfl_xor(a2, 32); a3 += __shfl_xor(a3, 32);
        a0 += __shfl_xor(a0, 16); a1 += __shfl_xor(a1, 16);
        a2 += __shfl_xor(a2, 16); a3 += __shfl_xor(a3, 16);
        if (g == 0) {
            float dn = rsqrtf((float)c + 1.0f);
            float4 bl = b4p[c16];
            float4 r;
            r.x = fmaxf(bl.x + dn * a0, 0.f);
            r.y = fmaxf(bl.y + dn * a1, 0.f);
            r.z = fmaxf(bl.z + dn * a2, 0.f);
            r.w = fmaxf(bl.w + dn * a3, 0.f);
            out4[(size_t)n * 16 + c16] = r;
        }
    }
}

// ---------------------------------------------------------------------------
extern "C" void kernel_launch(void* const* d_in, const int* in_sizes, int n_in,
                              void* d_out, int out_size, void* d_ws, size_t ws_size,
                              hipStream_t stream) {
    const float* x  = (const float*)d_in[0];
    const int*   ei = (const int*)d_in[1];   // [2, E] flat: src then dst
    const float* W  = (const float*)d_in[2];
    const float* b  = (const float*)d_in[3];

    const int* src = ei;
    const int* dst = ei + N_EDGES;
    float* out = (float*)d_out;

    // workspace: xwsh (6.4MB) | cursor padded (50KB) | binned (4.0MB) | Wt16 (8KB)
    f16*          xwsh   = (f16*)d_ws;
    int*          cursor = (int*)(xwsh + (size_t)N_NODES * D);
    unsigned int* binned = (unsigned int*)(cursor + NBUCK * CSTRIDE);
    f16*          Wt16   = (f16*)(binned + (size_t)NBUCK * CAP);

    hipMemsetAsync(cursor, 0, (size_t)NBUCK * CSTRIDE * sizeof(int), stream);
    partition_edges<<<NPART, 1024, 0, stream>>>(src, dst, cursor, binned, W, Wt16);
    xws_fused<<<NBUCK, 256, 0, stream>>>(cursor, binned, x, Wt16, xwsh);
    gather_out<<<NBUCK, 512, 0, stream>>>(cursor, binned, xwsh, b, out);
}